// Round 7
// baseline (582.871 us; speedup 1.0000x reference)
//
#include <hip/hip_runtime.h>
#include <stdint.h>

#define TB_ 32
#define C_ 256
#define N_ 3136
#define TBC (C_ * N_)            // 802816 elems per (t,b) per 256-ch tensor
#define ACT_SZ (TB_ * TBC)       // 25690112
#define XSB_TB 819200            // u16 elems per tb in blocked layout (200 groups * 4096)
#define PARTS 7
#define CHUNK 448                // 3136/7, multiple of 16

typedef __attribute__((ext_vector_type(8))) short bf16x8;
typedef __attribute__((ext_vector_type(4))) float f32x4;

__device__ __forceinline__ void glds16(const void* gp, void* lp) {
  __builtin_amdgcn_global_load_lds(
      (const __attribute__((address_space(1))) unsigned int*)gp,
      (__attribute__((address_space(3))) unsigned int*)lp, 16, 0, 0);
}

__device__ __forceinline__ unsigned short bf16rn(float f, float* val) {
  unsigned b = __float_as_uint(f);
  unsigned r = (b + 0x7fffu + ((b >> 16) & 1u)) >> 16;
  *val = __uint_as_float(r << 16);
  return (unsigned short)r;
}

__device__ __forceinline__ int dot4u(unsigned a, unsigned b, int c) {
  c += (int)(a & 255u)         * (int)(b & 255u);
  c += (int)((a >> 8) & 255u)  * (int)((b >> 8) & 255u);
  c += (int)((a >> 16) & 255u) * (int)((b >> 16) & 255u);
  c += (int)(a >> 24)          * (int)(b >> 24);
  return c;
}

__device__ __forceinline__ int dot4(unsigned a, unsigned b, int c) {
#if defined(__has_builtin)
#if __has_builtin(__builtin_amdgcn_sdot4)
  return __builtin_amdgcn_sdot4((int)a, (int)b, c, false);
#else
  return dot4u(a, b, c);
#endif
#else
  return dot4u(a, b, c);
#endif
}

// ---------------------------------------------------------------------------
// K0: fused prep — bx 0: BN fold; bx 1..1024: weight split; bx 1025..1056: kv zero
// ---------------------------------------------------------------------------
__global__ __launch_bounds__(256) void prep_all(
    const float* __restrict__ qbn, const float* __restrict__ kbn,
    const float* __restrict__ vbn, const float* __restrict__ pbn,
    const float* __restrict__ qw, const float* __restrict__ kw,
    const float* __restrict__ vw, const float* __restrict__ pw,
    float* __restrict__ bnw, unsigned short* __restrict__ wsp,
    unsigned short* __restrict__ osb) {
  const int bx = blockIdx.x;
  const int t = threadIdx.x;
  if (bx == 0) {
    const float* ps[4] = {qbn, kbn, vbn, pbn};
#pragma unroll
    for (int i = 0; i < 4; ++i) {
      const float* p = ps[i];
      float g = p[t], be = p[256 + t], mn = p[512 + t], vr = p[768 + t];
      float s = g / sqrtf(vr + 1e-5f);
      float b = __fsub_rn(be, __fmul_rn(mn, s));
      bnw[i * 512 + t] = s;
      bnw[i * 512 + 256 + t] = b;
    }
  } else if (bx <= 1024) {
    const float* Ws[4] = {qw, kw, vw, pw};
    int id = bx - 1, co = id & 255, m = id >> 8;
    float w = Ws[m][co * 256 + t];
    float h1, h2, h3r;
    unsigned short u1 = bf16rn(w, &h1);
    float r1 = __fsub_rn(w, h1);
    unsigned short u2 = bf16rn(r1, &h2);
    float r2 = __fsub_rn(r1, h2);
    unsigned short u3 = bf16rn(r2, &h3r);   // exact: r2 has <=8 significant bits
    int rt = co >> 7, ks = t >> 5;
    int lane = (co & 15) + 16 * ((t >> 3) & 3);
    unsigned short us[3] = {u1, u2, u3};
#pragma unroll
    for (int sp = 0; sp < 3; ++sp) {
      size_t off = (size_t)((((m * 3 + sp) * 2 + rt) * 8 + ks)) * 4096 + lane * 8 + (t & 7);
      wsp[off] = us[sp];
    }
  } else {
    int tb = bx - 1025;
    int4* p = (int4*)(osb + (size_t)tb * XSB_TB + 802816);
    for (int i = t; i < 2048; i += 256) p[i] = make_int4(0, 0, 0, 0);
  }
}

// ---------------------------------------------------------------------------
// K1: x -> spikes (bf16, exact 0..8) in blocked B-fragment layout.
// float4 global loads; LDS row stride 68 u16 keeps 8B alignment, staggered banks.
// ---------------------------------------------------------------------------
__global__ __launch_bounds__(256) void quant_x_t(const float* __restrict__ x,
                                                 unsigned short* __restrict__ xsb) {
  __shared__ unsigned short s[64 * 68];
  const int t = threadIdx.x;
  const int n0 = blockIdx.x * 64;
  const int tb = blockIdx.y;
  const float* X = x + (size_t)tb * TBC;
  const int nl = t & 63, cq = t >> 6;          // pack stage
  const int c16 = t >> 4, p4 = (t & 15) * 4;   // load stage

  unsigned short* dstb = xsb + (size_t)tb * XSB_TB;
  for (int cb = 0; cb < 4; ++cb) {
    int cbase = cb * 64;
#pragma unroll
    for (int i = 0; i < 4; ++i) {
      int c = i * 16 + c16;                    // 0..63 local
      float4 v = *(const float4*)&X[(size_t)(cbase + c) * N_ + n0 + p4];
      unsigned short r0 = (unsigned short)(__float_as_uint(fminf(fmaxf(rintf(v.x), 0.f), 8.f)) >> 16);
      unsigned short r1 = (unsigned short)(__float_as_uint(fminf(fmaxf(rintf(v.y), 0.f), 8.f)) >> 16);
      unsigned short r2 = (unsigned short)(__float_as_uint(fminf(fmaxf(rintf(v.z), 0.f), 8.f)) >> 16);
      unsigned short r3 = (unsigned short)(__float_as_uint(fminf(fmaxf(rintf(v.w), 0.f), 8.f)) >> 16);
      uint2 pk2;
      pk2.x = (unsigned)r0 | ((unsigned)r1 << 16);
      pk2.y = (unsigned)r2 | ((unsigned)r3 << 16);
      *(uint2*)&s[c * 68 + p4] = pk2;
    }
    __syncthreads();
#pragma unroll 2
    for (int j = 0; j < 2; ++j) {
      int ccl = j * 4 + cq;
      int cc = cb * 8 + ccl;
      unsigned short v8[8];
#pragma unroll
      for (int d = 0; d < 8; ++d) v8[d] = s[(ccl * 8 + d) * 68 + nl];
      int n = n0 + nl;
      uint4 pk;
      pk.x = (unsigned)v8[0] | ((unsigned)v8[1] << 16);
      pk.y = (unsigned)v8[2] | ((unsigned)v8[3] << 16);
      pk.z = (unsigned)v8[4] | ((unsigned)v8[5] << 16);
      pk.w = (unsigned)v8[6] | ((unsigned)v8[7] << 16);
      *(uint4*)&dstb[(size_t)(n >> 4) * 4096 + cc * 128 + (n & 15) * 8] = pk;
    }
    __syncthreads();
  }
}

// ---------------------------------------------------------------------------
// K2: one conv's GEMM (launched 3x). XCD swizzle: b = oct*16 + rt*8 + gl,
// rt-siblings share b%8 (same XCD). Per-block math identical to round 5/6.
// ---------------------------------------------------------------------------
__global__ __launch_bounds__(256) void qkv_conv(
    const unsigned short* __restrict__ xsb, const unsigned short* __restrict__ wsp,
    const float* __restrict__ bnw, uint8_t* __restrict__ outbase, int conv) {
  __shared__ __align__(16) char smem[16384];
  char* smA = smem;
  char* smB = smem + 8192;
  const int t = threadIdx.x;
  const int L = t & 63, w = t >> 6;
  const int wrow = w >> 1, wcol = w & 1;
  const int b = blockIdx.x;
  const int oct = b >> 4, rem = b & 15;
  const int rt = rem >> 3, gl = rem & 7;
  const int g = oct * 8 + gl;
  const int ntile = g % 25, tb = g / 25;
  const int n0 = ntile * 128;

  const char* Bb = (const char*)(xsb + (size_t)tb * XSB_TB) + (size_t)ntile * 65536;

  f32x4 acc[4][4];
#pragma unroll
  for (int i = 0; i < 4; ++i)
#pragma unroll
    for (int j = 0; j < 4; ++j) acc[i][j] = (f32x4){0.f, 0.f, 0.f, 0.f};

  for (int sp = 0; sp < 3; ++sp) {
    const char* Asp = (const char*)wsp + ((size_t)(conv * 3 + sp) * 16 + rt * 8) * 8192;
#pragma unroll 1
    for (int ks2 = 0; ks2 < 8; ++ks2) {
      __syncthreads();
      const char* Ak = Asp + ks2 * 8192;
      glds16(Ak + t * 16, smA + t * 16);
      glds16(Ak + t * 16 + 4096, smA + t * 16 + 4096);
      const char* Bk = Bb + ks2 * 1024;
      glds16(Bk + (size_t)w * 8192 + L * 16, smB + t * 16);
      glds16(Bk + (size_t)(w + 4) * 8192 + L * 16, smB + t * 16 + 4096);
      __syncthreads();
      bf16x8 af[4], bfr[4];
#pragma unroll
      for (int i = 0; i < 4; ++i) {
        af[i] = *(const bf16x8*)(smA + (wrow * 4 + i) * 1024 + L * 16);
        bfr[i] = *(const bf16x8*)(smB + (wcol * 4 + i) * 1024 + L * 16);
      }
#pragma unroll
      for (int i = 0; i < 4; ++i)
#pragma unroll
        for (int j = 0; j < 4; ++j)
          acc[i][j] = __builtin_amdgcn_mfma_f32_16x16x32_bf16(af[i], bfr[j], acc[i][j], 0, 0, 0);
    }
  }

  uint8_t* outp = outbase + (size_t)tb * TBC;
  const float* sbn = bnw + conv * 512;
  const int rbase = rt * 128;
#pragma unroll
  for (int i = 0; i < 4; ++i) {
    int co0 = rbase + wrow * 64 + i * 16 + ((L >> 4) << 2);
#pragma unroll
    for (int j = 0; j < 4; ++j) {
      int n = n0 + wcol * 64 + j * 16 + (L & 15);
      if (n < N_) {
#pragma unroll
        for (int r = 0; r < 4; ++r) {
          int co = co0 + r;
          float y = acc[i][j][r] * 0.125f;
          float tt = __fadd_rn(__fmul_rn(y, sbn[co]), sbn[256 + co]);
          float rr = fminf(fmaxf(rintf(tt), 0.f), 8.f);
          outp[(size_t)co * N_ + n] = (uint8_t)rr;
        }
      }
    }
  }
}

// ---------------------------------------------------------------------------
// K3b: partial kv = k^T v over an n-chunk, exact i32 atomics. grid (8,32,PARTS)
// ---------------------------------------------------------------------------
__global__ __launch_bounds__(256) void attn_kv(
    const uint8_t* __restrict__ ks, const uint8_t* __restrict__ vs,
    unsigned short* __restrict__ osb) {
  const int h = blockIdx.x, tb = blockIdx.y, part = blockIdx.z;
  const int tid = threadIdx.x;
  __shared__ unsigned sk[32][64];
  __shared__ unsigned sv[32][64];
  const uint8_t* K = ks + (size_t)tb * TBC + h * 32 * N_;
  const uint8_t* V = vs + (size_t)tb * TBC + h * 32 * N_;
  const int d0 = (tid >> 4) * 2;
  const int e0 = (tid & 15) * 2;
  const int pbase = part * CHUNK;
  const int pend = pbase + CHUNK;
  int acc[2][2] = {};

  for (int nt = 0; nt < 2; ++nt) {     // 448 = 256 + 192
    int n0 = pbase + nt * 256;
    if (n0 >= pend) break;
    if (nt) __syncthreads();
#pragma unroll
    for (int i = 0; i < 8; ++i) {
      int idx = tid + i * 256;
      int d = idx >> 6, w2 = idx & 63;
      int n = n0 + w2 * 4;
      unsigned kw_ = 0, vw_ = 0;
      if (n < pend) {
        kw_ = *(const unsigned*)&K[d * N_ + n];
        vw_ = *(const unsigned*)&V[d * N_ + n];
      }
      sk[d][w2] = kw_;
      sv[d][w2] = vw_;
    }
    __syncthreads();
#pragma unroll
    for (int w2 = 0; w2 < 64; w2 += 4) {
      uint4 ka = *(const uint4*)&sk[d0][w2];
      uint4 kb = *(const uint4*)&sk[d0 + 1][w2];
      uint4 va = *(const uint4*)&sv[e0][w2];
      uint4 vb = *(const uint4*)&sv[e0 + 1][w2];
      unsigned kwds[2][4] = {{ka.x, ka.y, ka.z, ka.w}, {kb.x, kb.y, kb.z, kb.w}};
      unsigned vwds[2][4] = {{va.x, va.y, va.z, va.w}, {vb.x, vb.y, vb.z, vb.w}};
#pragma unroll
      for (int di = 0; di < 2; ++di)
#pragma unroll
        for (int ej = 0; ej < 2; ++ej)
#pragma unroll
          for (int c = 0; c < 4; ++c)
            acc[di][ej] = dot4(kwds[di][c], vwds[ej][c], acc[di][ej]);
    }
  }
  int* dst = (int*)(osb + (size_t)tb * XSB_TB + 802816) + h * 1024;
  atomicAdd(&dst[d0 * 32 + e0], acc[0][0]);
  atomicAdd(&dst[d0 * 32 + e0 + 1], acc[0][1]);
  atomicAdd(&dst[(d0 + 1) * 32 + e0], acc[1][0]);
  atomicAdd(&dst[(d0 + 1) * 32 + e0 + 1], acc[1][1]);
}

// ---------------------------------------------------------------------------
// K3c: o = quant(q . kv * scale) -> blocked bf16 layout, LDS repack +
// coalesced uint4 stores. grid (8,32,PARTS)
// ---------------------------------------------------------------------------
__global__ __launch_bounds__(256) void attn_o(
    const uint8_t* __restrict__ qs, unsigned short* __restrict__ osb) {
  const int h = blockIdx.x, tb = blockIdx.y, part = blockIdx.z;
  const int tid = threadIdx.x;
  __shared__ uint8_t sq[256][48];
  __shared__ __align__(16) unsigned short so[16 * 544];  // [gi][eq*136 + n16*8 + e7]
  const uint8_t* Q = qs + (size_t)tb * TBC + h * 32 * N_;
  unsigned short* osb_tb = osb + (size_t)tb * XSB_TB;
  const int e = tid & 31;
  const int g2 = tid >> 5;
  const int eq = e >> 3, e7 = e & 7;
  const int* kvp = (const int*)(osb + (size_t)tb * XSB_TB + 802816) + h * 1024;
  int kvcol[32];
#pragma unroll
  for (int d = 0; d < 32; ++d) kvcol[d] = kvp[d * 32 + e];

  const float cscale = (float)(0.3535533905932738 / 512.0);
  const int pbase = part * CHUNK;
  const int pend = pbase + CHUNK;

  for (int nt = 0; nt < 2; ++nt) {
    int n0 = pbase + nt * 256;
    if (n0 >= pend) break;
    if (nt) __syncthreads();
#pragma unroll
    for (int i = 0; i < 8; ++i) {
      int idx = tid + i * 256;
      int d = idx >> 6, w2 = idx & 63;
      int n = n0 + w2 * 4;
      unsigned qw_ = 0;
      if (n < pend) qw_ = *(const unsigned*)&Q[d * N_ + n];
      sq[w2 * 4 + 0][d] = (uint8_t)(qw_ & 255u);
      sq[w2 * 4 + 1][d] = (uint8_t)((qw_ >> 8) & 255u);
      sq[w2 * 4 + 2][d] = (uint8_t)((qw_ >> 16) & 255u);
      sq[w2 * 4 + 3][d] = (uint8_t)(qw_ >> 24);
    }
    __syncthreads();
#pragma unroll
    for (int s8 = 0; s8 < 8; ++s8) {
      int nl = (s8 * 8 + g2) * 4;
      int n = n0 + nl;
      if (n >= pend) continue;
      unsigned short* sop = &so[(nl >> 4) * 544 + eq * 136 + (nl & 15) * 8 + e7];
#pragma unroll
      for (int jn = 0; jn < 4; ++jn) {
        const uint8_t* qrow = &sq[nl + jn][0];
        uint4 qa = *(const uint4*)&qrow[0];
        uint4 qb = *(const uint4*)&qrow[16];
        unsigned qq[8] = {qa.x, qa.y, qa.z, qa.w, qb.x, qb.y, qb.z, qb.w};
        int o = 0;
#pragma unroll
        for (int qi = 0; qi < 8; ++qi)
#pragma unroll
          for (int m = 0; m < 4; ++m)
            o += (int)((qq[qi] >> (8 * m)) & 255u) * kvcol[qi * 4 + m];
        float of = (float)o * cscale;
        float r = fminf(fmaxf(rintf(of), 0.f), 8.f);
        sop[jn * 8] = (unsigned short)(__float_as_uint(r) >> 16);
      }
    }
    __syncthreads();
    int ngroups = (pend - n0) >> 4;
    if (ngroups > 16) ngroups = 16;
    int g0 = n0 >> 4;
#pragma unroll
    for (int i = 0; i < 4; ++i) {
      int idx = tid + i * 256;      // 0..1023
      int gi = idx >> 6, r = idx & 63;
      if (gi < ngroups) {
        int eqq = r >> 4, rest = (r & 15) * 8;
        uint4 v = *(const uint4*)&so[gi * 544 + eqq * 136 + rest];
        *(uint4*)&osb_tb[(size_t)(g0 + gi) * 4096 + h * 512 + r * 8] = v;
      }
    }
  }
}

// ---------------------------------------------------------------------------
// K4: out = BN(pw @ os/8) via bf16 MFMA, 2 splits. XCD swizzle.
// ---------------------------------------------------------------------------
__global__ __launch_bounds__(256) void out_mfma_sw(
    const unsigned short* __restrict__ osb, const unsigned short* __restrict__ wsp,
    const float* __restrict__ bnw, float* __restrict__ out) {
  __shared__ __align__(16) char smem[16384];
  char* smA = smem;
  char* smB = smem + 8192;
  const int t = threadIdx.x;
  const int L = t & 63, w = t >> 6;
  const int wrow = w >> 1, wcol = w & 1;
  const int b = blockIdx.x;
  const int oct = b / 16, rem = b % 16;
  const int rt = rem >> 3, gl = rem & 7;
  const int g = oct * 8 + gl;
  const int ntile = g % 25, tb = g / 25;
  const int n0 = ntile * 128;
  const char* Bb = (const char*)(osb + (size_t)tb * XSB_TB) + (size_t)ntile * 65536;

  f32x4 acc[4][4];
#pragma unroll
  for (int i = 0; i < 4; ++i)
#pragma unroll
    for (int j = 0; j < 4; ++j) acc[i][j] = (f32x4){0.f, 0.f, 0.f, 0.f};

  for (int sp = 0; sp < 2; ++sp) {
    const char* Asp = (const char*)wsp + ((size_t)(9 + sp) * 16 + rt * 8) * 8192;
#pragma unroll 1
    for (int ks2 = 0; ks2 < 8; ++ks2) {
      __syncthreads();
      const char* Ak = Asp + ks2 * 8192;
      glds16(Ak + t * 16, smA + t * 16);
      glds16(Ak + t * 16 + 4096, smA + t * 16 + 4096);
      const char* Bk = Bb + ks2 * 1024;
      glds16(Bk + (size_t)w * 8192 + L * 16, smB + t * 16);
      glds16(Bk + (size_t)(w + 4) * 8192 + L * 16, smB + t * 16 + 4096);
      __syncthreads();
      bf16x8 af[4], bfr[4];
#pragma unroll
      for (int i = 0; i < 4; ++i) {
        af[i] = *(const bf16x8*)(smA + (wrow * 4 + i) * 1024 + L * 16);
        bfr[i] = *(const bf16x8*)(smB + (wcol * 4 + i) * 1024 + L * 16);
      }
#pragma unroll
      for (int i = 0; i < 4; ++i)
#pragma unroll
        for (int j = 0; j < 4; ++j)
          acc[i][j] = __builtin_amdgcn_mfma_f32_16x16x32_bf16(af[i], bfr[j], acc[i][j], 0, 0, 0);
    }
  }

  float* O = out + (size_t)tb * TBC;
  const float* sbn = bnw + 3 * 512;
  const int rbase = rt * 128;
#pragma unroll
  for (int i = 0; i < 4; ++i) {
    int co0 = rbase + wrow * 64 + i * 16 + ((L >> 4) << 2);
#pragma unroll
    for (int j = 0; j < 4; ++j) {
      int n = n0 + wcol * 64 + j * 16 + (L & 15);
      if (n < N_) {
#pragma unroll
        for (int r = 0; r < 4; ++r) {
          int co = co0 + r;
          float y = acc[i][j][r] * 0.125f;
          O[(size_t)co * N_ + n] = __fadd_rn(__fmul_rn(y, sbn[co]), sbn[256 + co]);
        }
      }
    }
  }
}

// ---------------------------------------------------------------------------
extern "C" void kernel_launch(void* const* d_in, const int* in_sizes, int n_in,
                              void* d_out, int out_size, void* d_ws, size_t ws_size,
                              hipStream_t stream) {
  const float* x   = (const float*)d_in[0];
  const float* qw  = (const float*)d_in[1];
  const float* qbn = (const float*)d_in[2];
  const float* kw  = (const float*)d_in[3];
  const float* kbn = (const float*)d_in[4];
  const float* vw  = (const float*)d_in[5];
  const float* vbn = (const float*)d_in[6];
  const float* pw  = (const float*)d_in[7];
  const float* pbn = (const float*)d_in[8];
  float* out = (float*)d_out;

  uint8_t* ws = (uint8_t*)d_ws;
  float* bnw           = (float*)ws;                         // 8 KB
  unsigned short* wsp  = (unsigned short*)(ws + 8192);       // 1.57 MB
  unsigned short* xsb  = (unsigned short*)(ws + 1581056);    // 52.4 MB blocked spikes
  uint8_t* qsp = ws + 54009856;
  uint8_t* ksp = qsp + ACT_SZ;
  uint8_t* vsp = ksp + ACT_SZ;                               // ends at 131,080,192
  unsigned short* osb = xsb;   // alias: xsb dead after qkv; kv scratch in osb padding groups

  prep_all<<<1057, 256, 0, stream>>>(qbn, kbn, vbn, pbn, qw, kw, vw, pw, bnw, wsp, osb);
  quant_x_t<<<dim3(49, 32), 256, 0, stream>>>(x, xsb);
  qkv_conv<<<1600, 256, 0, stream>>>(xsb, wsp, bnw, qsp, 0);
  qkv_conv<<<1600, 256, 0, stream>>>(xsb, wsp, bnw, ksp, 1);
  qkv_conv<<<1600, 256, 0, stream>>>(xsb, wsp, bnw, vsp, 2);
  attn_kv<<<dim3(8, 32, PARTS), 256, 0, stream>>>(ksp, vsp, osb);
  attn_o<<<dim3(8, 32, PARTS), 256, 0, stream>>>(qsp, osb);
  out_mfma_sw<<<1600, 256, 0, stream>>>(osb, wsp, bnw, out);
}

// Round 8
// 434.467 us; speedup vs baseline: 1.3416x; 1.3416x over previous
//
#include <hip/hip_runtime.h>
#include <stdint.h>

#define TB_ 32
#define C_ 256
#define N_ 3136
#define TBC (C_ * N_)            // 802816 elems per (t,b) per 256-ch tensor
#define ACT_SZ (TB_ * TBC)       // 25690112
#define XSB_TB 819200            // elems per tb in blocked layouts (200 groups * 4096)
#define PARTS 7
#define CHUNK 448                // 3136/7, multiple of 16

typedef __attribute__((ext_vector_type(8))) short bf16x8;
typedef __attribute__((ext_vector_type(4))) float f32x4;

__device__ __forceinline__ void glds16(const void* gp, void* lp) {
  __builtin_amdgcn_global_load_lds(
      (const __attribute__((address_space(1))) unsigned int*)gp,
      (__attribute__((address_space(3))) unsigned int*)lp, 16, 0, 0);
}

__device__ __forceinline__ unsigned short bf16rn(float f, float* val) {
  unsigned b = __float_as_uint(f);
  unsigned r = (b + 0x7fffu + ((b >> 16) & 1u)) >> 16;
  *val = __uint_as_float(r << 16);
  return (unsigned short)r;
}

__device__ __forceinline__ int dot4u(unsigned a, unsigned b, int c) {
  c += (int)(a & 255u)         * (int)(b & 255u);
  c += (int)((a >> 8) & 255u)  * (int)((b >> 8) & 255u);
  c += (int)((a >> 16) & 255u) * (int)((b >> 16) & 255u);
  c += (int)(a >> 24)          * (int)(b >> 24);
  return c;
}

__device__ __forceinline__ int dot4(unsigned a, unsigned b, int c) {
#if defined(__has_builtin)
#if __has_builtin(__builtin_amdgcn_sdot4)
  return __builtin_amdgcn_sdot4((int)a, (int)b, c, false);
#else
  return dot4u(a, b, c);
#endif
#else
  return dot4u(a, b, c);
#endif
}

// ---------------------------------------------------------------------------
// K0: fused prep — bx 0: BN fold; 1..1024: weight split; 1025..1056: kvg zero
// ---------------------------------------------------------------------------
__global__ __launch_bounds__(256) void prep_all(
    const float* __restrict__ qbn, const float* __restrict__ kbn,
    const float* __restrict__ vbn, const float* __restrict__ pbn,
    const float* __restrict__ qw, const float* __restrict__ kw,
    const float* __restrict__ vw, const float* __restrict__ pw,
    float* __restrict__ bnw, unsigned short* __restrict__ wsp,
    int* __restrict__ kvg) {
  const int bx = blockIdx.x;
  const int t = threadIdx.x;
  if (bx == 0) {
    const float* ps[4] = {qbn, kbn, vbn, pbn};
#pragma unroll
    for (int i = 0; i < 4; ++i) {
      const float* p = ps[i];
      float g = p[t], be = p[256 + t], mn = p[512 + t], vr = p[768 + t];
      float s = g / sqrtf(vr + 1e-5f);
      float b = __fsub_rn(be, __fmul_rn(mn, s));
      bnw[i * 512 + t] = s;
      bnw[i * 512 + 256 + t] = b;
    }
  } else if (bx <= 1024) {
    const float* Ws[4] = {qw, kw, vw, pw};
    int id = bx - 1, co = id & 255, m = id >> 8;
    float w = Ws[m][co * 256 + t];
    float h1, h2, h3r;
    unsigned short u1 = bf16rn(w, &h1);
    float r1 = __fsub_rn(w, h1);
    unsigned short u2 = bf16rn(r1, &h2);
    float r2 = __fsub_rn(r1, h2);
    unsigned short u3 = bf16rn(r2, &h3r);   // exact: r2 has <=8 significant bits
    int rt = co >> 7, ks = t >> 5;
    int lane = (co & 15) + 16 * ((t >> 3) & 3);
    unsigned short us[3] = {u1, u2, u3};
#pragma unroll
    for (int sp = 0; sp < 3; ++sp) {
      size_t off = (size_t)((((m * 3 + sp) * 2 + rt) * 8 + ks)) * 4096 + lane * 8 + (t & 7);
      wsp[off] = us[sp];
    }
  } else {
    int tb = bx - 1025;
    int4* p = (int4*)(kvg + (size_t)tb * 8192);
    for (int i = t; i < 2048; i += 256) p[i] = make_int4(0, 0, 0, 0);
  }
}

// ---------------------------------------------------------------------------
// K1: x -> spikes (bf16, exact 0..8) in blocked B-fragment layout (float4 loads)
// ---------------------------------------------------------------------------
__global__ __launch_bounds__(256) void quant_x_t(const float* __restrict__ x,
                                                 unsigned short* __restrict__ xsb) {
  __shared__ unsigned short s[64 * 68];
  const int t = threadIdx.x;
  const int n0 = blockIdx.x * 64;
  const int tb = blockIdx.y;
  const float* X = x + (size_t)tb * TBC;
  const int nl = t & 63, cq = t >> 6;
  const int c16 = t >> 4, p4 = (t & 15) * 4;

  unsigned short* dstb = xsb + (size_t)tb * XSB_TB;
  for (int cb = 0; cb < 4; ++cb) {
    int cbase = cb * 64;
#pragma unroll
    for (int i = 0; i < 4; ++i) {
      int c = i * 16 + c16;
      float4 v = *(const float4*)&X[(size_t)(cbase + c) * N_ + n0 + p4];
      unsigned short r0 = (unsigned short)(__float_as_uint(fminf(fmaxf(rintf(v.x), 0.f), 8.f)) >> 16);
      unsigned short r1 = (unsigned short)(__float_as_uint(fminf(fmaxf(rintf(v.y), 0.f), 8.f)) >> 16);
      unsigned short r2 = (unsigned short)(__float_as_uint(fminf(fmaxf(rintf(v.z), 0.f), 8.f)) >> 16);
      unsigned short r3 = (unsigned short)(__float_as_uint(fminf(fmaxf(rintf(v.w), 0.f), 8.f)) >> 16);
      uint2 pk2;
      pk2.x = (unsigned)r0 | ((unsigned)r1 << 16);
      pk2.y = (unsigned)r2 | ((unsigned)r3 << 16);
      *(uint2*)&s[c * 68 + p4] = pk2;
    }
    __syncthreads();
#pragma unroll 2
    for (int j = 0; j < 2; ++j) {
      int ccl = j * 4 + cq;
      int cc = cb * 8 + ccl;
      unsigned short v8[8];
#pragma unroll
      for (int d = 0; d < 8; ++d) v8[d] = s[(ccl * 8 + d) * 68 + nl];
      int n = n0 + nl;
      uint4 pk;
      pk.x = (unsigned)v8[0] | ((unsigned)v8[1] << 16);
      pk.y = (unsigned)v8[2] | ((unsigned)v8[3] << 16);
      pk.z = (unsigned)v8[4] | ((unsigned)v8[5] << 16);
      pk.w = (unsigned)v8[6] | ((unsigned)v8[7] << 16);
      *(uint4*)&dstb[(size_t)(n >> 4) * 4096 + cc * 128 + (n & 15) * 8] = pk;
    }
    __syncthreads();
  }
}

// ---------------------------------------------------------------------------
// K2: fused q/k/v GEMM (round-5 proven XCD swizzle, 4800 blocks). conv0
// writes q as u8-BLOCKED (for attn_o's MFMA staging); conv1/2 planar u8.
// ---------------------------------------------------------------------------
__global__ __launch_bounds__(256) void qkv_mfma_sw(
    const unsigned short* __restrict__ xsb, const unsigned short* __restrict__ wsp,
    const float* __restrict__ bnw,
    uint8_t* __restrict__ qsb, uint8_t* __restrict__ ks_, uint8_t* __restrict__ vs) {
  __shared__ __align__(16) char smem[16384];
  char* smA = smem;
  char* smB = smem + 8192;
  const int t = threadIdx.x;
  const int L = t & 63, w = t >> 6;
  const int wrow = w >> 1, wcol = w & 1;
  const int b = blockIdx.x;
  const int oct = b / 48, rem = b % 48;
  const int s = rem >> 3, gl = rem & 7;
  const int g = oct * 8 + gl;
  const int ntile = g % 25, tb = g / 25;
  const int conv = s >> 1, rt = s & 1;
  const int n0 = ntile * 128;

  const char* Bb = (const char*)(xsb + (size_t)tb * XSB_TB) + (size_t)ntile * 65536;

  f32x4 acc[4][4];
#pragma unroll
  for (int i = 0; i < 4; ++i)
#pragma unroll
    for (int j = 0; j < 4; ++j) acc[i][j] = (f32x4){0.f, 0.f, 0.f, 0.f};

  for (int sp = 0; sp < 3; ++sp) {
    const char* Asp = (const char*)wsp + ((size_t)(conv * 3 + sp) * 16 + rt * 8) * 8192;
#pragma unroll 1
    for (int ks2 = 0; ks2 < 8; ++ks2) {
      __syncthreads();
      const char* Ak = Asp + ks2 * 8192;
      glds16(Ak + t * 16, smA + t * 16);
      glds16(Ak + t * 16 + 4096, smA + t * 16 + 4096);
      const char* Bk = Bb + ks2 * 1024;
      glds16(Bk + (size_t)w * 8192 + L * 16, smB + t * 16);
      glds16(Bk + (size_t)(w + 4) * 8192 + L * 16, smB + t * 16 + 4096);
      __syncthreads();
      bf16x8 af[4], bfr[4];
#pragma unroll
      for (int i = 0; i < 4; ++i) {
        af[i] = *(const bf16x8*)(smA + (wrow * 4 + i) * 1024 + L * 16);
        bfr[i] = *(const bf16x8*)(smB + (wcol * 4 + i) * 1024 + L * 16);
      }
#pragma unroll
      for (int i = 0; i < 4; ++i)
#pragma unroll
        for (int j = 0; j < 4; ++j)
          acc[i][j] = __builtin_amdgcn_mfma_f32_16x16x32_bf16(af[i], bfr[j], acc[i][j], 0, 0, 0);
    }
  }

  const float* sbn = bnw + conv * 512;
  const int rbase = rt * 128;
  if (conv == 0) {
    uint8_t* qtb = qsb + (size_t)tb * XSB_TB;   // u8 blocked, same group layout
#pragma unroll
    for (int i = 0; i < 4; ++i) {
      int co0 = rbase + wrow * 64 + i * 16 + ((L >> 4) << 2);
      float s0 = sbn[co0], b0 = sbn[256 + co0];
      float s1 = sbn[co0 + 1], b1 = sbn[256 + co0 + 1];
      float s2 = sbn[co0 + 2], b2 = sbn[256 + co0 + 2];
      float s3 = sbn[co0 + 3], b3 = sbn[256 + co0 + 3];
#pragma unroll
      for (int j = 0; j < 4; ++j) {
        int n = n0 + wcol * 64 + j * 16 + (L & 15);
        if (n < N_) {
          float ss[4] = {s0, s1, s2, s3}, bb[4] = {b0, b1, b2, b3};
          unsigned wb = 0;
#pragma unroll
          for (int r = 0; r < 4; ++r) {
            float y = acc[i][j][r] * 0.125f;
            float tt = __fadd_rn(__fmul_rn(y, ss[r]), bb[r]);
            float rr = fminf(fmaxf(rintf(tt), 0.f), 8.f);
            wb |= ((unsigned)(uint8_t)rr) << (8 * r);
          }
          *(unsigned*)&qtb[(size_t)(n >> 4) * 4096 + (co0 >> 3) * 128 + (n & 15) * 8 + (co0 & 7)] = wb;
        }
      }
    }
  } else {
    uint8_t* outp = (conv == 1 ? ks_ : vs) + (size_t)tb * TBC;
#pragma unroll
    for (int i = 0; i < 4; ++i) {
      int co0 = rbase + wrow * 64 + i * 16 + ((L >> 4) << 2);
#pragma unroll
      for (int j = 0; j < 4; ++j) {
        int n = n0 + wcol * 64 + j * 16 + (L & 15);
        if (n < N_) {
#pragma unroll
          for (int r = 0; r < 4; ++r) {
            int co = co0 + r;
            float y = acc[i][j][r] * 0.125f;
            float tt = __fadd_rn(__fmul_rn(y, sbn[co]), sbn[256 + co]);
            float rr = fminf(fmaxf(rintf(tt), 0.f), 8.f);
            outp[(size_t)co * N_ + n] = (uint8_t)rr;
          }
        }
      }
    }
  }
}

// ---------------------------------------------------------------------------
// K3: partial kv = k^T v, exact i32 atomics. Padded LDS rows (68 u32) break
// the 16-way conflict on the v-read (now 4-way). grid (8,32,PARTS)
// ---------------------------------------------------------------------------
__global__ __launch_bounds__(256) void attn_kv(
    const uint8_t* __restrict__ ks, const uint8_t* __restrict__ vs,
    int* __restrict__ kvg) {
  const int h = blockIdx.x, tb = blockIdx.y, part = blockIdx.z;
  const int tid = threadIdx.x;
  __shared__ unsigned sk[32][68];
  __shared__ unsigned sv[32][68];
  const uint8_t* K = ks + (size_t)tb * TBC + h * 32 * N_;
  const uint8_t* V = vs + (size_t)tb * TBC + h * 32 * N_;
  const int d0 = (tid >> 4) * 2;
  const int e0 = (tid & 15) * 2;
  const int pbase = part * CHUNK;
  const int pend = pbase + CHUNK;
  int acc[2][2] = {};

  for (int nt = 0; nt < 2; ++nt) {
    int n0 = pbase + nt * 256;
    if (n0 >= pend) break;
    if (nt) __syncthreads();
#pragma unroll
    for (int i = 0; i < 8; ++i) {
      int idx = tid + i * 256;
      int d = idx >> 6, w2 = idx & 63;
      int n = n0 + w2 * 4;
      unsigned kw_ = 0, vw_ = 0;
      if (n < pend) {
        kw_ = *(const unsigned*)&K[d * N_ + n];
        vw_ = *(const unsigned*)&V[d * N_ + n];
      }
      sk[d][w2] = kw_;
      sv[d][w2] = vw_;
    }
    __syncthreads();
#pragma unroll
    for (int w2 = 0; w2 < 64; w2 += 4) {
      uint4 ka = *(const uint4*)&sk[d0][w2];
      uint4 kb = *(const uint4*)&sk[d0 + 1][w2];
      uint4 va = *(const uint4*)&sv[e0][w2];
      uint4 vb = *(const uint4*)&sv[e0 + 1][w2];
      unsigned kwds[2][4] = {{ka.x, ka.y, ka.z, ka.w}, {kb.x, kb.y, kb.z, kb.w}};
      unsigned vwds[2][4] = {{va.x, va.y, va.z, va.w}, {vb.x, vb.y, vb.z, vb.w}};
#pragma unroll
      for (int di = 0; di < 2; ++di)
#pragma unroll
        for (int ej = 0; ej < 2; ++ej)
#pragma unroll
          for (int c = 0; c < 4; ++c)
            acc[di][ej] = dot4(kwds[di][c], vwds[ej][c], acc[di][ej]);
    }
  }
  int* dst = kvg + ((size_t)(tb * 8 + h)) * 1024;
  atomicAdd(&dst[d0 * 32 + e0], acc[0][0]);
  atomicAdd(&dst[d0 * 32 + e0 + 1], acc[0][1]);
  atomicAdd(&dst[(d0 + 1) * 32 + e0], acc[1][0]);
  atomicAdd(&dst[(d0 + 1) * 32 + e0 + 1], acc[1][1]);
}

// ---------------------------------------------------------------------------
// K3b: split kv ints (< 2^18, nonneg) into 3 truncation-exact bf16 parts,
// laid out as MFMA A-fragment images: kvimg[tb][h][sp][mtile][lane][j].
// A[m=e][k=d]: mtile=e>>4, lane=(e&15)+16*(d>>3), j=d&7.
// ---------------------------------------------------------------------------
__global__ __launch_bounds__(256) void kv_finish(const int* __restrict__ kvg,
                                                 unsigned short* __restrict__ kvimg) {
  const int tb = blockIdx.x, t = threadIdx.x;
  const int* src = kvg + (size_t)tb * 8192;
  unsigned short* dst = kvimg + (size_t)tb * 24576;
#pragma unroll 4
  for (int i = 0; i < 32; ++i) {
    int idx = t + i * 256;
    int h = idx >> 10, rem = idx & 1023, d = rem >> 5, e = rem & 31;
    int v = src[idx];
    int b1 = (v > 0) ? (32 - __clz(v)) : 0;
    int sh1 = b1 > 8 ? b1 - 8 : 0;
    int hi = (v >> sh1) << sh1;
    int r1 = v - hi;
    int b2 = (r1 > 0) ? (32 - __clz(r1)) : 0;
    int sh2 = b2 > 8 ? b2 - 8 : 0;
    int mid = (r1 >> sh2) << sh2;
    int r2 = r1 - mid;
    int parts[3] = {hi, mid, r2};
    int mtile = e >> 4, lane = (e & 15) + 16 * (d >> 3), j = d & 7;
#pragma unroll
    for (int sp = 0; sp < 3; ++sp) {
      float f = (float)parts[sp];   // exact: <=8 significant bits
      dst[(size_t)h * 3072 + (sp * 2 + mtile) * 512 + lane * 8 + j] =
          (unsigned short)(__float_as_uint(f) >> 16);
    }
  }
}

// ---------------------------------------------------------------------------
// K3c: o = quant(q . kv * scale) via bf16 MFMA. Per block (ntile,tb), loop
// 8 heads: glds16 A-images (6KB), unpack u8-blocked q -> bf16 B-image (8KB),
// 48 MFMAs/head split across 4 waves (2 nfrags each). Exact post-quant
// (nonneg terms; values < 2^24 exact, larger clip to 8). grid 800.
// ---------------------------------------------------------------------------
__global__ __launch_bounds__(256) void attn_o_mfma(
    const uint8_t* __restrict__ qsb, const unsigned short* __restrict__ kvimg,
    unsigned short* __restrict__ osb) {
  __shared__ __align__(16) char smem[14336];   // 8KB B-image + 6KB A-images
  char* smB = smem;
  char* smA = smem + 8192;
  const int t = threadIdx.x;
  const int L = t & 63, wv = t >> 6;
  const int b = blockIdx.x;
  const int ntile = b % 25, tb = b / 25;
  const uint8_t* Q = qsb + (size_t)tb * XSB_TB + (size_t)ntile * 8 * 4096;
  const unsigned short* KV = kvimg + (size_t)tb * 24576;
  unsigned short* osb_tb = osb + (size_t)tb * XSB_TB;
  const float cscale = (float)(0.3535533905932738 / 512.0);

#pragma unroll 1
  for (int h = 0; h < 8; ++h) {
    __syncthreads();
    // A-images: 6 KB via glds16
    const char* Ah = (const char*)(KV + (size_t)h * 3072);
    glds16(Ah + t * 16, smA + t * 16);
    if (t < 128) glds16(Ah + 4096 + t * 16, smA + 4096 + t * 16);
    // B-image: unpack u8-blocked q (head slice) -> bf16 fragment image
#pragma unroll
    for (int it = 0; it < 4; ++it) {
      int w2 = t + it * 256;                 // 0..1023 u32 words
      int gl2 = w2 >> 7;                     // group 0..7
      int wl = w2 & 127;
      int ccp = wl >> 5;                     // local k>>3
      int rem = (w2 * 4) & 127;
      int n16 = rem >> 3, k7b = rem & 7;     // k7b in {0,4}
      unsigned wd = *(const unsigned*)&Q[(size_t)gl2 * 4096 + (h * 4 + ccp) * 128 + n16 * 8 + k7b];
      unsigned short* ds = (unsigned short*)smB + gl2 * 512 + (ccp * 16 + n16) * 8 + k7b;
      float f0 = (float)(wd & 255u), f1 = (float)((wd >> 8) & 255u);
      float f2 = (float)((wd >> 16) & 255u), f3 = (float)(wd >> 24);
      uint2 pk;
      pk.x = (__float_as_uint(f0) >> 16) | ((__float_as_uint(f1) >> 16) << 16);
      pk.y = (__float_as_uint(f2) >> 16) | ((__float_as_uint(f3) >> 16) << 16);
      *(uint2*)ds = pk;
    }
    __syncthreads();
    // per-wave: 2 nfrags (j = wv*2 + jj)
    bf16x8 bfr[2];
#pragma unroll
    for (int jj = 0; jj < 2; ++jj)
      bfr[jj] = *(const bf16x8*)(smB + (wv * 2 + jj) * 1024 + L * 16);
    f32x4 acc[2][2];
#pragma unroll
    for (int i = 0; i < 2; ++i)
#pragma unroll
      for (int jj = 0; jj < 2; ++jj) acc[i][jj] = (f32x4){0.f, 0.f, 0.f, 0.f};
#pragma unroll
    for (int sp = 0; sp < 3; ++sp) {
      bf16x8 a0 = *(const bf16x8*)(smA + (sp * 2 + 0) * 1024 + L * 16);
      bf16x8 a1 = *(const bf16x8*)(smA + (sp * 2 + 1) * 1024 + L * 16);
#pragma unroll
      for (int jj = 0; jj < 2; ++jj) {
        acc[0][jj] = __builtin_amdgcn_mfma_f32_16x16x32_bf16(a0, bfr[jj], acc[0][jj], 0, 0, 0);
        acc[1][jj] = __builtin_amdgcn_mfma_f32_16x16x32_bf16(a1, bfr[jj], acc[1][jj], 0, 0, 0);
      }
    }
    // epilogue: e = i*16 + (L>>4)*4 + r, n = ntile*128 + (wv*2+jj)*16 + (L&15)
#pragma unroll
    for (int i = 0; i < 2; ++i) {
      int c0 = h * 32 + i * 16 + ((L >> 4) << 2);
#pragma unroll
      for (int jj = 0; jj < 2; ++jj) {
        int n = ntile * 128 + (wv * 2 + jj) * 16 + (L & 15);
        if (n < N_) {
          unsigned short u[4];
#pragma unroll
          for (int r = 0; r < 4; ++r) {
            float of = acc[i][jj][r] * cscale;
            float rr = fminf(fmaxf(rintf(of), 0.f), 8.f);
            u[r] = (unsigned short)(__float_as_uint(rr) >> 16);
          }
          uint2 pk;
          pk.x = (unsigned)u[0] | ((unsigned)u[1] << 16);
          pk.y = (unsigned)u[2] | ((unsigned)u[3] << 16);
          *(uint2*)&osb_tb[(size_t)(n >> 4) * 4096 + (c0 >> 3) * 128 + (n & 15) * 8 + (c0 & 7)] = pk;
        }
      }
    }
  }
}

// ---------------------------------------------------------------------------
// K4: out = BN(pw @ os/8) via bf16 MFMA, 2 splits, XCD swizzle (round-6 form)
// ---------------------------------------------------------------------------
__global__ __launch_bounds__(256) void out_mfma_sw(
    const unsigned short* __restrict__ osb, const unsigned short* __restrict__ wsp,
    const float* __restrict__ bnw, float* __restrict__ out) {
  __shared__ __align__(16) char smem[16384];
  char* smA = smem;
  char* smB = smem + 8192;
  const int t = threadIdx.x;
  const int L = t & 63, w = t >> 6;
  const int wrow = w >> 1, wcol = w & 1;
  const int b = blockIdx.x;
  const int oct = b / 16, rem = b % 16;
  const int rt = rem >> 3, gl = rem & 7;
  const int g = oct * 8 + gl;
  const int ntile = g % 25, tb = g / 25;
  const int n0 = ntile * 128;
  const char* Bb = (const char*)(osb + (size_t)tb * XSB_TB) + (size_t)ntile * 65536;

  f32x4 acc[4][4];
#pragma unroll
  for (int i = 0; i < 4; ++i)
#pragma unroll
    for (int j = 0; j < 4; ++j) acc[i][j] = (f32x4){0.f, 0.f, 0.f, 0.f};

  for (int sp = 0; sp < 2; ++sp) {
    const char* Asp = (const char*)wsp + ((size_t)(9 + sp) * 16 + rt * 8) * 8192;
#pragma unroll 1
    for (int ks2 = 0; ks2 < 8; ++ks2) {
      __syncthreads();
      const char* Ak = Asp + ks2 * 8192;
      glds16(Ak + t * 16, smA + t * 16);
      glds16(Ak + t * 16 + 4096, smA + t * 16 + 4096);
      const char* Bk = Bb + ks2 * 1024;
      glds16(Bk + (size_t)w * 8192 + L * 16, smB + t * 16);
      glds16(Bk + (size_t)(w + 4) * 8192 + L * 16, smB + t * 16 + 4096);
      __syncthreads();
      bf16x8 af[4], bfr[4];
#pragma unroll
      for (int i = 0; i < 4; ++i) {
        af[i] = *(const bf16x8*)(smA + (wrow * 4 + i) * 1024 + L * 16);
        bfr[i] = *(const bf16x8*)(smB + (wcol * 4 + i) * 1024 + L * 16);
      }
#pragma unroll
      for (int i = 0; i < 4; ++i)
#pragma unroll
        for (int j = 0; j < 4; ++j)
          acc[i][j] = __builtin_amdgcn_mfma_f32_16x16x32_bf16(af[i], bfr[j], acc[i][j], 0, 0, 0);
    }
  }

  float* O = out + (size_t)tb * TBC;
  const float* sbn = bnw + 3 * 512;
  const int rbase = rt * 128;
#pragma unroll
  for (int i = 0; i < 4; ++i) {
    int co0 = rbase + wrow * 64 + i * 16 + ((L >> 4) << 2);
#pragma unroll
    for (int j = 0; j < 4; ++j) {
      int n = n0 + wcol * 64 + j * 16 + (L & 15);
      if (n < N_) {
#pragma unroll
        for (int r = 0; r < 4; ++r) {
          int co = co0 + r;
          float y = acc[i][j][r] * 0.125f;
          O[(size_t)co * N_ + n] = __fadd_rn(__fmul_rn(y, sbn[co]), sbn[256 + co]);
        }
      }
    }
  }
}

// ---------------------------------------------------------------------------
extern "C" void kernel_launch(void* const* d_in, const int* in_sizes, int n_in,
                              void* d_out, int out_size, void* d_ws, size_t ws_size,
                              hipStream_t stream) {
  const float* x   = (const float*)d_in[0];
  const float* qw  = (const float*)d_in[1];
  const float* qbn = (const float*)d_in[2];
  const float* kw  = (const float*)d_in[3];
  const float* kbn = (const float*)d_in[4];
  const float* vw  = (const float*)d_in[5];
  const float* vbn = (const float*)d_in[6];
  const float* pw  = (const float*)d_in[7];
  const float* pbn = (const float*)d_in[8];
  float* out = (float*)d_out;

  uint8_t* ws = (uint8_t*)d_ws;
  float* bnw           = (float*)ws;                           // 8 KB
  unsigned short* wsp  = (unsigned short*)(ws + 8192);         // 1.57 MB
  unsigned short* xsb  = (unsigned short*)(ws + 1581056);      // 52.43 MB
  uint8_t* qsb         = ws + 54009856;                        // 26.21 MB u8 blocked q
  uint8_t* ksp         = ws + 80224256;                        // 25.69 MB
  uint8_t* vsp         = ws + 105914368;                       // 25.69 MB
  int* kvg             = (int*)(ws + 131604480);               // 1.05 MB
  unsigned short* kvimg = (unsigned short*)(ws + 132653056);   // 1.57 MB -> ends 134.2 MB
  unsigned short* osb  = xsb;   // alias: xsb dead after qkv

  prep_all<<<1057, 256, 0, stream>>>(qbn, kbn, vbn, pbn, qw, kw, vw, pw, bnw, wsp, kvg);
  quant_x_t<<<dim3(49, 32), 256, 0, stream>>>(x, xsb);
  qkv_mfma_sw<<<4800, 256, 0, stream>>>(xsb, wsp, bnw, qsb, ksp, vsp);
  attn_kv<<<dim3(8, 32, PARTS), 256, 0, stream>>>(ksp, vsp, kvg);
  kv_finish<<<32, 256, 0, stream>>>(kvg, kvimg);
  attn_o_mfma<<<800, 256, 0, stream>>>(qsb, kvimg, osb);
  out_mfma_sw<<<1600, 256, 0, stream>>>(osb, wsp, bnw, out);
}